// Round 1
// baseline (556.357 us; speedup 1.0000x reference)
//
#include <hip/hip_runtime.h>
#include <math.h>

namespace {

constexpr int SEQ    = 1024;
constexpr int DMODEL = 1024;
constexpr int DINNER = 2048;
constexpr int DSTATE = 16;
constexpr int DTRANK = 64;
constexpr int XPW    = 96;   // DTRANK + 2*DSTATE

__device__ __forceinline__ float siluf(float x) { return x / (1.f + __expf(-x)); }

// C[M][N] = A[M][K] @ B[N][K]^T   (both operands K-contiguous, row-major)
// EPI: 0 = plain store, 1 = softplus(v + bias[n])
template<int BM, int BN, int BK, int TM, int TN, int EPI>
__global__ __launch_bounds__(256)
void gemm_nt(const float* __restrict__ A, int lda,
             const float* __restrict__ B, int ldb,
             float* __restrict__ C, int ldc,
             const float* __restrict__ bias, int K)
{
    constexpr int CT = BN / TN;          // threads along n
    constexpr int RT = BM / TM;          // threads along m
    static_assert(CT * RT == 256, "need 256 threads");
    static_assert(BM * BK == 1024, "A tile = 4 floats/thread");
    static_assert(TM == 4, "float4 LDS read on A");

    __shared__ float As[BK][BM + 4];     // K-major, +4 pad keeps rows 16B-aligned
    __shared__ float Bs[BK][BN + 4];

    const int tid = threadIdx.x;
    const int tx  = tid % CT;
    const int ty  = tid / CT;
    const int m0  = blockIdx.y * BM;
    const int n0  = blockIdx.x * BN;

    float acc[TM][TN];
#pragma unroll
    for (int i = 0; i < TM; ++i)
#pragma unroll
        for (int j = 0; j < TN; ++j) acc[i][j] = 0.f;

    const int arow = tid >> 2;           // 0..63
    const int acol = (tid & 3) << 2;     // 0,4,8,12

    for (int k0 = 0; k0 < K; k0 += BK) {
        float4 av = *reinterpret_cast<const float4*>(
            &A[(size_t)(m0 + arow) * lda + k0 + acol]);
        As[acol + 0][arow] = av.x;
        As[acol + 1][arow] = av.y;
        As[acol + 2][arow] = av.z;
        As[acol + 3][arow] = av.w;
        if constexpr (BN * BK == 1024) {
            float4 bv = *reinterpret_cast<const float4*>(
                &B[(size_t)(n0 + arow) * ldb + k0 + acol]);
            Bs[acol + 0][arow] = bv.x;
            Bs[acol + 1][arow] = bv.y;
            Bs[acol + 2][arow] = bv.z;
            Bs[acol + 3][arow] = bv.w;
        } else {
            constexpr int CNT = BN * BK / 256;
#pragma unroll
            for (int i = 0; i < CNT; ++i) {
                int e  = tid + i * 256;
                int br = e / BK, bc = e % BK;
                Bs[bc][br] = B[(size_t)(n0 + br) * ldb + k0 + bc];
            }
        }
        __syncthreads();
#pragma unroll
        for (int k = 0; k < BK; ++k) {
            float ar[TM], br[TN];
            float4 a4 = *reinterpret_cast<const float4*>(&As[k][ty * TM]);
            ar[0] = a4.x; ar[1] = a4.y; ar[2] = a4.z; ar[3] = a4.w;
            if constexpr (TN == 4) {
                float4 b4 = *reinterpret_cast<const float4*>(&Bs[k][tx * TN]);
                br[0] = b4.x; br[1] = b4.y; br[2] = b4.z; br[3] = b4.w;
            } else {
                float2 b2 = *reinterpret_cast<const float2*>(&Bs[k][tx * TN]);
                br[0] = b2.x; br[1] = b2.y;
            }
#pragma unroll
            for (int i = 0; i < TM; ++i)
#pragma unroll
                for (int j = 0; j < TN; ++j)
                    acc[i][j] = fmaf(ar[i], br[j], acc[i][j]);
        }
        __syncthreads();
    }

#pragma unroll
    for (int i = 0; i < TM; ++i) {
        const int row = m0 + ty * TM + i;
        float v[TN];
#pragma unroll
        for (int j = 0; j < TN; ++j) {
            float t = acc[i][j];
            if constexpr (EPI == 1) {
                t += bias[n0 + tx * TN + j];
                t = (t > 20.f) ? t : log1pf(__expf(t));   // softplus
            }
            v[j] = t;
        }
        if constexpr (TN == 4) {
            float4 o{v[0], v[1], v[2], v[3]};
            *reinterpret_cast<float4*>(&C[(size_t)row * ldc + n0 + tx * TN]) = o;
        } else {
            float2 o{v[0], v[1]};
            *reinterpret_cast<float2*>(&C[(size_t)row * ldc + n0 + tx * TN]) = o;
        }
    }
}

// causal depthwise conv (width 4) + bias + silu.  xi lives in xz[:, 0:2048].
__global__ __launch_bounds__(256)
void conv_silu(const float* __restrict__ xz,
               const float* __restrict__ conv_w,
               const float* __restrict__ conv_b,
               float* __restrict__ xic)
{
    int idx = blockIdx.x * 256 + threadIdx.x;   // over SEQ*DINNER
    int l = idx / DINNER;
    int d = idx % DINNER;
    float acc = conv_b[d];
    float4 w = *reinterpret_cast<const float4*>(&conv_w[d * 4]);
    float wk[4] = {w.x, w.y, w.z, w.w};
#pragma unroll
    for (int k = 0; k < 4; ++k) {
        int ls = l - 3 + k;
        if (ls >= 0) acc = fmaf(xz[(size_t)ls * (2 * DINNER) + d], wk[k], acc);
    }
    xic[idx] = siluf(acc);
}

// selective scan over L, fused with D_skip + silu(z) gate.
// block = 256 threads = 16 d-channels x 16 state lanes; h in registers.
__global__ __launch_bounds__(256)
void scan_kernel(const float* __restrict__ delta,   // [SEQ][DINNER]
                 const float* __restrict__ xic,     // [SEQ][DINNER]
                 const float* __restrict__ xdbl,    // [SEQ][XPW]  (B at 64, C at 80)
                 const float* __restrict__ A_log,   // [DINNER][16]
                 const float* __restrict__ D_skip,  // [DINNER]
                 const float* __restrict__ xz,      // [SEQ][2*DINNER] (z at 2048)
                 float* __restrict__ yfin)          // [SEQ][DINNER]
{
    const int tid = threadIdx.x;
    const int n   = tid & 15;        // state index
    const int dd  = tid >> 4;        // local channel 0..15
    const int d0  = blockIdx.x * 16;
    const int d   = d0 + dd;

    const float Aneg = -__expf(A_log[d * DSTATE + n]);
    float h = 0.f;

    __shared__ float ds[16][16], xs[16][16], Bsh[16][16], Csh[16][16], ys[16][17];

    const int lr = tid >> 4;   // staging row (time)
    const int lc = tid & 15;   // staging col

    for (int t0 = 0; t0 < SEQ; t0 += 16) {
        ds[lr][lc]  = delta[(size_t)(t0 + lr) * DINNER + d0 + lc];
        xs[lr][lc]  = xic  [(size_t)(t0 + lr) * DINNER + d0 + lc];
        Bsh[lr][lc] = xdbl [(size_t)(t0 + lr) * XPW + DTRANK + lc];
        Csh[lr][lc] = xdbl [(size_t)(t0 + lr) * XPW + DTRANK + DSTATE + lc];
        __syncthreads();
#pragma unroll
        for (int tt = 0; tt < 16; ++tt) {
            float dl = ds[tt][dd];
            float xv = xs[tt][dd];
            float a  = __expf(dl * Aneg);
            h = fmaf(a, h, dl * xv * Bsh[tt][n]);
            float py = h * Csh[tt][n];
            py += __shfl_xor(py, 1);
            py += __shfl_xor(py, 2);
            py += __shfl_xor(py, 4);
            py += __shfl_xor(py, 8);
            if (n == 0) ys[tt][dd] = py;
        }
        __syncthreads();
        {   // fused epilogue: (y + xi*D) * silu(z)
            int t  = t0 + lr;
            int dg = d0 + lc;
            float yv  = ys[lr][lc];
            float xiv = xs[lr][lc];
            float zv  = xz[(size_t)t * (2 * DINNER) + DINNER + dg];
            yfin[(size_t)t * DINNER + dg] = fmaf(xiv, D_skip[dg], yv) * siluf(zv);
        }
        __syncthreads();
    }
}

}  // namespace

extern "C" void kernel_launch(void* const* d_in, const int* in_sizes, int n_in,
                              void* d_out, int out_size, void* d_ws, size_t ws_size,
                              hipStream_t stream)
{
    (void)in_sizes; (void)n_in; (void)out_size; (void)ws_size;

    const float* x       = (const float*)d_in[0];
    const float* W_in    = (const float*)d_in[1];
    const float* conv_w  = (const float*)d_in[2];
    const float* conv_b  = (const float*)d_in[3];
    const float* W_xproj = (const float*)d_in[4];
    const float* W_dt    = (const float*)d_in[5];
    const float* b_dt    = (const float*)d_in[6];
    const float* A_log   = (const float*)d_in[7];
    const float* D_skip  = (const float*)d_in[8];
    const float* W_out   = (const float*)d_in[9];
    float* out = (float*)d_out;

    float* ws    = (float*)d_ws;
    float* xz    = ws;                                  // SEQ * 4096
    float* xic   = xz   + (size_t)SEQ * 2 * DINNER;     // SEQ * 2048
    float* xdbl  = xic  + (size_t)SEQ * DINNER;         // SEQ * 96
    float* delta = xdbl + (size_t)SEQ * XPW;            // SEQ * 2048
    float* yfin  = delta + (size_t)SEQ * DINNER;        // SEQ * 2048

    // 1) xz = x @ W_in^T          (1024 x 4096, K=1024)
    gemm_nt<64, 64, 16, 4, 4, 0><<<dim3(2 * DINNER / 64, SEQ / 64), 256, 0, stream>>>(
        x, DMODEL, W_in, DMODEL, xz, 2 * DINNER, nullptr, DMODEL);

    // 2) causal depthwise conv + silu
    conv_silu<<<(SEQ * DINNER) / 256, 256, 0, stream>>>(xz, conv_w, conv_b, xic);

    // 3) x_dbl = xic @ W_xproj^T  (1024 x 96, K=2048)
    gemm_nt<64, 32, 16, 4, 2, 0><<<dim3(XPW / 32, SEQ / 64), 256, 0, stream>>>(
        xic, DINNER, W_xproj, DINNER, xdbl, XPW, nullptr, DINNER);

    // 4) delta = softplus(dt @ W_dt^T + b_dt)   (1024 x 2048, K=64)
    gemm_nt<64, 64, 16, 4, 4, 1><<<dim3(DINNER / 64, SEQ / 64), 256, 0, stream>>>(
        xdbl, XPW, W_dt, DTRANK, delta, DINNER, b_dt, DTRANK);

    // 5) selective scan + gate fusion
    scan_kernel<<<DINNER / 16, 256, 0, stream>>>(
        delta, xic, xdbl, A_log, D_skip, xz, yfin);

    // 6) out = y @ W_out^T        (1024 x 1024, K=2048)
    gemm_nt<64, 64, 16, 4, 4, 0><<<dim3(DMODEL / 64, SEQ / 64), 256, 0, stream>>>(
        yfin, DINNER, W_out, DINNER, out, DMODEL, nullptr, DINNER);
}

// Round 2
// 379.440 us; speedup vs baseline: 1.4663x; 1.4663x over previous
//
#include <hip/hip_runtime.h>
#include <math.h>

namespace {

constexpr int SEQ    = 1024;
constexpr int DMODEL = 1024;
constexpr int DINNER = 2048;
constexpr int DSTATE = 16;
constexpr int DTRANK = 64;
constexpr int XPW    = 96;   // DTRANK + 2*DSTATE
constexpr int CH     = 64;   // scan chunk length
constexpr int NC     = SEQ / CH;  // 16 chunks

__device__ __forceinline__ float siluf(float x) { return x / (1.f + __expf(-x)); }

// C[M][N] = A[M][K] @ B[N][K]^T   (both operands K-contiguous, row-major)
// EPI: 0 = plain store, 1 = softplus(v + bias[n])
template<int BM, int BN, int BK, int TM, int TN, int EPI>
__global__ __launch_bounds__(256)
void gemm_nt(const float* __restrict__ A, int lda,
             const float* __restrict__ B, int ldb,
             float* __restrict__ C, int ldc,
             const float* __restrict__ bias, int K)
{
    constexpr int CT = BN / TN;          // threads along n
    constexpr int RT = BM / TM;          // threads along m
    static_assert(CT * RT == 256, "need 256 threads");
    static_assert(BM * BK == 1024, "A tile = 4 floats/thread");
    static_assert(TM == 4, "float4 LDS read on A");

    __shared__ float As[BK][BM + 4];     // K-major, +4 pad keeps rows 16B-aligned
    __shared__ float Bs[BK][BN + 4];

    const int tid = threadIdx.x;
    const int tx  = tid % CT;
    const int ty  = tid / CT;
    const int m0  = blockIdx.y * BM;
    const int n0  = blockIdx.x * BN;

    float acc[TM][TN];
#pragma unroll
    for (int i = 0; i < TM; ++i)
#pragma unroll
        for (int j = 0; j < TN; ++j) acc[i][j] = 0.f;

    const int arow = tid >> 2;           // 0..63
    const int acol = (tid & 3) << 2;     // 0,4,8,12

    for (int k0 = 0; k0 < K; k0 += BK) {
        float4 av = *reinterpret_cast<const float4*>(
            &A[(size_t)(m0 + arow) * lda + k0 + acol]);
        As[acol + 0][arow] = av.x;
        As[acol + 1][arow] = av.y;
        As[acol + 2][arow] = av.z;
        As[acol + 3][arow] = av.w;
        if constexpr (BN * BK == 1024) {
            float4 bv = *reinterpret_cast<const float4*>(
                &B[(size_t)(n0 + arow) * ldb + k0 + acol]);
            Bs[acol + 0][arow] = bv.x;
            Bs[acol + 1][arow] = bv.y;
            Bs[acol + 2][arow] = bv.z;
            Bs[acol + 3][arow] = bv.w;
        } else {
            constexpr int CNT = BN * BK / 256;
#pragma unroll
            for (int i = 0; i < CNT; ++i) {
                int e  = tid + i * 256;
                int br = e / BK, bc = e % BK;
                Bs[bc][br] = B[(size_t)(n0 + br) * ldb + k0 + bc];
            }
        }
        __syncthreads();
#pragma unroll
        for (int k = 0; k < BK; ++k) {
            float ar[TM], br[TN];
            float4 a4 = *reinterpret_cast<const float4*>(&As[k][ty * TM]);
            ar[0] = a4.x; ar[1] = a4.y; ar[2] = a4.z; ar[3] = a4.w;
            if constexpr (TN == 4) {
                float4 b4 = *reinterpret_cast<const float4*>(&Bs[k][tx * TN]);
                br[0] = b4.x; br[1] = b4.y; br[2] = b4.z; br[3] = b4.w;
            } else {
                float2 b2 = *reinterpret_cast<const float2*>(&Bs[k][tx * TN]);
                br[0] = b2.x; br[1] = b2.y;
            }
#pragma unroll
            for (int i = 0; i < TM; ++i)
#pragma unroll
                for (int j = 0; j < TN; ++j)
                    acc[i][j] = fmaf(ar[i], br[j], acc[i][j]);
        }
        __syncthreads();
    }

#pragma unroll
    for (int i = 0; i < TM; ++i) {
        const int row = m0 + ty * TM + i;
        float v[TN];
#pragma unroll
        for (int j = 0; j < TN; ++j) {
            float t = acc[i][j];
            if constexpr (EPI == 1) {
                t += bias[n0 + tx * TN + j];
                t = (t > 20.f) ? t : log1pf(__expf(t));   // softplus
            }
            v[j] = t;
        }
        if constexpr (TN == 4) {
            float4 o{v[0], v[1], v[2], v[3]};
            *reinterpret_cast<float4*>(&C[(size_t)row * ldc + n0 + tx * TN]) = o;
        } else {
            float2 o{v[0], v[1]};
            *reinterpret_cast<float2*>(&C[(size_t)row * ldc + n0 + tx * TN]) = o;
        }
    }
}

// causal depthwise conv (width 4) + bias + silu.  xi lives in xz[:, 0:2048].
__global__ __launch_bounds__(256)
void conv_silu(const float* __restrict__ xz,
               const float* __restrict__ conv_w,
               const float* __restrict__ conv_b,
               float* __restrict__ xic)
{
    int idx = blockIdx.x * 256 + threadIdx.x;   // over SEQ*DINNER
    int l = idx / DINNER;
    int d = idx % DINNER;
    float acc = conv_b[d];
    float4 w = *reinterpret_cast<const float4*>(&conv_w[d * 4]);
    float wk[4] = {w.x, w.y, w.z, w.w};
#pragma unroll
    for (int k = 0; k < 4; ++k) {
        int ls = l - 3 + k;
        if (ls >= 0) acc = fmaf(xz[(size_t)ls * (2 * DINNER) + d], wk[k], acc);
    }
    xic[idx] = siluf(acc);
}

// ---------------- chunk-parallel selective scan ----------------
// Recurrence per (d,n): h_t = a_t h_{t-1} + b_t, a_t = exp(delta_t A),
// b_t = delta_t x_t B_t.  Chunk decay product P = exp(A * sum(delta)) (exact).

// Pass 1: per (d,n,chunk): P (chunk decay) and S (chunk-local end state, h_in=0)
__global__ __launch_bounds__(256)
void scan_pass1(const float* __restrict__ delta,
                const float* __restrict__ xic,
                const float* __restrict__ xdbl,
                const float* __restrict__ A_log,
                float* __restrict__ Pbuf,    // [NC][DINNER][16]
                float* __restrict__ Sbuf)    // [NC][DINNER][16]
{
    const int tid = threadIdx.x;
    const int n   = tid & 15;
    const int dd  = tid >> 4;
    const int d0  = blockIdx.x * 16;
    const int d   = d0 + dd;
    const int c   = blockIdx.y;
    const int tb  = c * CH;

    const float Aneg = -__expf(A_log[d * DSTATE + n]);
    float h = 0.f, sdl = 0.f;

    __shared__ float ds[16][16], xs[16][16], Bsh[16][16];
    const int lr = tid >> 4, lc = tid & 15;

    for (int t0 = 0; t0 < CH; t0 += 16) {
        int t = tb + t0 + lr;
        ds[lr][lc]  = delta[(size_t)t * DINNER + d0 + lc];
        xs[lr][lc]  = xic  [(size_t)t * DINNER + d0 + lc];
        Bsh[lr][lc] = xdbl [(size_t)t * XPW + DTRANK + lc];
        __syncthreads();
#pragma unroll
        for (int tt = 0; tt < 16; ++tt) {
            float dl = ds[tt][dd];
            float xv = xs[tt][dd];
            float a  = __expf(dl * Aneg);
            h = fmaf(a, h, dl * xv * Bsh[tt][n]);
            sdl += dl;
        }
        __syncthreads();
    }
    size_t o = ((size_t)c * DINNER + d) * 16 + n;
    Pbuf[o] = __expf(sdl * Aneg);
    Sbuf[o] = h;
}

// Pass 2: serial scan over chunk summaries -> h_in per chunk
__global__ __launch_bounds__(256)
void scan_pass2(const float* __restrict__ Pbuf,
                const float* __restrict__ Sbuf,
                float* __restrict__ Hin)     // [NC][DINNER][16]
{
    int idx = blockIdx.x * 256 + threadIdx.x;   // over DINNER*16
    float h = 0.f;
#pragma unroll
    for (int c = 0; c < NC; ++c) {
        size_t o = (size_t)c * (DINNER * DSTATE) + idx;
        Hin[o] = h;
        h = fmaf(Pbuf[o], h, Sbuf[o]);
    }
}

// Pass 3: recompute within-chunk with correct h_in; emit gated output.
__global__ __launch_bounds__(256)
void scan_pass3(const float* __restrict__ delta,
                const float* __restrict__ xic,
                const float* __restrict__ xdbl,
                const float* __restrict__ A_log,
                const float* __restrict__ D_skip,
                const float* __restrict__ xz,      // z at [:, 2048:]
                const float* __restrict__ Hin,
                float* __restrict__ yfin)
{
    const int tid = threadIdx.x;
    const int n   = tid & 15;
    const int dd  = tid >> 4;
    const int d0  = blockIdx.x * 16;
    const int d   = d0 + dd;
    const int c   = blockIdx.y;
    const int tb  = c * CH;

    const float Aneg = -__expf(A_log[d * DSTATE + n]);
    float h = Hin[((size_t)c * DINNER + d) * 16 + n];

    __shared__ float ds[16][16], xs[16][16], Bsh[16][16], Csh[16][16], ys[16][17];
    const int lr = tid >> 4, lc = tid & 15;

    for (int t0 = 0; t0 < CH; t0 += 16) {
        int t = tb + t0 + lr;
        ds[lr][lc]  = delta[(size_t)t * DINNER + d0 + lc];
        xs[lr][lc]  = xic  [(size_t)t * DINNER + d0 + lc];
        Bsh[lr][lc] = xdbl [(size_t)t * XPW + DTRANK + lc];
        Csh[lr][lc] = xdbl [(size_t)t * XPW + DTRANK + DSTATE + lc];
        __syncthreads();
#pragma unroll
        for (int tt = 0; tt < 16; ++tt) {
            float dl = ds[tt][dd];
            float xv = xs[tt][dd];
            float a  = __expf(dl * Aneg);
            h = fmaf(a, h, dl * xv * Bsh[tt][n]);
            float py = h * Csh[tt][n];
            py += __shfl_xor(py, 1);
            py += __shfl_xor(py, 2);
            py += __shfl_xor(py, 4);
            py += __shfl_xor(py, 8);
            if (n == 0) ys[tt][dd] = py;
        }
        __syncthreads();
        {   // fused epilogue: (y + xi*D) * silu(z)
            int t2 = tb + t0 + lr;
            int dg = d0 + lc;
            float yv  = ys[lr][lc];
            float xiv = xs[lr][lc];
            float zv  = xz[(size_t)t2 * (2 * DINNER) + DINNER + dg];
            yfin[(size_t)t2 * DINNER + dg] = fmaf(xiv, D_skip[dg], yv) * siluf(zv);
        }
        __syncthreads();
    }
}

}  // namespace

extern "C" void kernel_launch(void* const* d_in, const int* in_sizes, int n_in,
                              void* d_out, int out_size, void* d_ws, size_t ws_size,
                              hipStream_t stream)
{
    (void)in_sizes; (void)n_in; (void)out_size; (void)ws_size;

    const float* x       = (const float*)d_in[0];
    const float* W_in    = (const float*)d_in[1];
    const float* conv_w  = (const float*)d_in[2];
    const float* conv_b  = (const float*)d_in[3];
    const float* W_xproj = (const float*)d_in[4];
    const float* W_dt    = (const float*)d_in[5];
    const float* b_dt    = (const float*)d_in[6];
    const float* A_log   = (const float*)d_in[7];
    const float* D_skip  = (const float*)d_in[8];
    const float* W_out   = (const float*)d_in[9];
    float* out = (float*)d_out;

    float* ws    = (float*)d_ws;
    float* xz    = ws;                                  // SEQ * 4096
    float* xic   = xz    + (size_t)SEQ * 2 * DINNER;    // SEQ * 2048
    float* xdbl  = xic   + (size_t)SEQ * DINNER;        // SEQ * 96
    float* delta = xdbl  + (size_t)SEQ * XPW;           // SEQ * 2048
    float* yfin  = delta + (size_t)SEQ * DINNER;        // SEQ * 2048
    float* Pbuf  = yfin  + (size_t)SEQ * DINNER;        // NC * DINNER * 16
    float* Sbuf  = Pbuf  + (size_t)NC * DINNER * DSTATE;
    float* Hin   = Sbuf  + (size_t)NC * DINNER * DSTATE;

    // 1) xz = x @ W_in^T          (1024 x 4096, K=1024)
    gemm_nt<64, 64, 16, 4, 4, 0><<<dim3(2 * DINNER / 64, SEQ / 64), 256, 0, stream>>>(
        x, DMODEL, W_in, DMODEL, xz, 2 * DINNER, nullptr, DMODEL);

    // 2) causal depthwise conv + silu
    conv_silu<<<(SEQ * DINNER) / 256, 256, 0, stream>>>(xz, conv_w, conv_b, xic);

    // 3) x_dbl = xic @ W_xproj^T  (1024 x 96, K=2048)
    gemm_nt<64, 32, 16, 4, 2, 0><<<dim3(XPW / 32, SEQ / 64), 256, 0, stream>>>(
        xic, DINNER, W_xproj, DINNER, xdbl, XPW, nullptr, DINNER);

    // 4) delta = softplus(dt @ W_dt^T + b_dt)   (1024 x 2048, K=64)
    gemm_nt<64, 64, 16, 4, 4, 1><<<dim3(DINNER / 64, SEQ / 64), 256, 0, stream>>>(
        xdbl, XPW, W_dt, DTRANK, delta, DINNER, b_dt, DTRANK);

    // 5) chunk-parallel selective scan + gate fusion
    scan_pass1<<<dim3(DINNER / 16, NC), 256, 0, stream>>>(
        delta, xic, xdbl, A_log, Pbuf, Sbuf);
    scan_pass2<<<(DINNER * DSTATE) / 256, 256, 0, stream>>>(Pbuf, Sbuf, Hin);
    scan_pass3<<<dim3(DINNER / 16, NC), 256, 0, stream>>>(
        delta, xic, xdbl, A_log, D_skip, xz, Hin, yfin);

    // 6) out = y @ W_out^T        (1024 x 1024, K=2048)
    gemm_nt<64, 64, 16, 4, 4, 0><<<dim3(DMODEL / 64, SEQ / 64), 256, 0, stream>>>(
        yfin, DINNER, W_out, DINNER, out, DMODEL, nullptr, DINNER);
}

// Round 3
// 221.061 us; speedup vs baseline: 2.5168x; 1.7165x over previous
//
#include <hip/hip_runtime.h>
#include <hip/hip_bf16.h>
#include <math.h>

namespace {

constexpr int SEQ    = 1024;
constexpr int DMODEL = 1024;
constexpr int DINNER = 2048;
constexpr int DSTATE = 16;
constexpr int DTRANK = 64;
constexpr int XPW    = 96;        // DTRANK + 2*DSTATE (padded to 128 in bf16 buf)
constexpr int XPWP   = 128;
constexpr int CH     = 64;        // scan chunk length
constexpr int NC     = SEQ / CH;  // 16 chunks

typedef __attribute__((ext_vector_type(8))) short short8;
typedef __attribute__((ext_vector_type(4))) float floatx4;

#define GLB __attribute__((address_space(1)))
#define LDS __attribute__((address_space(3)))

__device__ __forceinline__ float siluf(float x) { return x / (1.f + __expf(-x)); }

__device__ __forceinline__ unsigned short f2b(float f) {
    __hip_bfloat16 h = __float2bfloat16(f);
    return *reinterpret_cast<unsigned short*>(&h);
}
__device__ __forceinline__ float b2f(unsigned short u) {
    union { unsigned int i; float f; } v; v.i = (unsigned int)u << 16; return v.f;
}

// ---------------- casts ----------------
__global__ __launch_bounds__(256)
void cast_bf16(const float* __restrict__ in, unsigned short* __restrict__ out) {
    int i = (blockIdx.x * 256 + threadIdx.x) * 8;
    float4 a = *reinterpret_cast<const float4*>(&in[i]);
    float4 b = *reinterpret_cast<const float4*>(&in[i + 4]);
    short8 o;
    o[0] = (short)f2b(a.x); o[1] = (short)f2b(a.y); o[2] = (short)f2b(a.z); o[3] = (short)f2b(a.w);
    o[4] = (short)f2b(b.x); o[5] = (short)f2b(b.y); o[6] = (short)f2b(b.z); o[7] = (short)f2b(b.w);
    *reinterpret_cast<short8*>(&out[i]) = o;
}

// W_xproj [96][2048] f32 -> [128][2048] bf16, rows 96..127 zero
__global__ __launch_bounds__(256)
void cast_pad_xproj(const float* __restrict__ in, unsigned short* __restrict__ out) {
    int i = (blockIdx.x * 256 + threadIdx.x) * 8;   // over 128*2048
    int row = i / DINNER;
    short8 o;
    if (row < XPW) {
        float4 a = *reinterpret_cast<const float4*>(&in[i]);
        float4 b = *reinterpret_cast<const float4*>(&in[i + 4]);
        o[0] = (short)f2b(a.x); o[1] = (short)f2b(a.y); o[2] = (short)f2b(a.z); o[3] = (short)f2b(a.w);
        o[4] = (short)f2b(b.x); o[5] = (short)f2b(b.y); o[6] = (short)f2b(b.z); o[7] = (short)f2b(b.w);
    } else {
        for (int j = 0; j < 8; ++j) o[j] = 0;
    }
    *reinterpret_cast<short8*>(&out[i]) = o;
}

// ---------------- bf16 MFMA GEMM:  C[M][N] = A[M][K] @ B[N][K]^T ----------------
// 128x128 tile, BK=32, 4 waves (2x2), each wave 64x64 = 4x4 frags of 16x16x32.
// EPI: 0 = f32 store, 1 = softplus(v + bias[n]) f32 store, 2 = bf16 store.
template<int BM, int BN, int EPI, typename OutT>
__global__ __launch_bounds__(256)
void gemm_mfma(const unsigned short* __restrict__ A, int lda,
               const unsigned short* __restrict__ B, int ldb,
               OutT* __restrict__ C, int ldc,
               const float* __restrict__ bias, int K)
{
    constexpr int BK = 32;
    constexpr int MR = BM / 32, NR = BN / 32;
    __shared__ unsigned short Alds[BM * BK];
    __shared__ unsigned short Blds[BN * BK];

    const int tid  = threadIdx.x;
    const int lane = tid & 63;
    const int wv   = tid >> 6;
    const int wm   = wv >> 1, wn = wv & 1;
    const int fr   = lane & 15;      // frag row (A-M) / col (B-N / C-N)
    const int kg   = lane >> 4;      // k-group 0..3
    const int m0   = blockIdx.y * BM;
    const int n0   = blockIdx.x * BN;

    const int srow = tid >> 2;           // staging: 64 rows / round
    const int scol = (tid & 3) * 8;      // 8 bf16 = 16B per lane

    floatx4 acc[MR][NR];
#pragma unroll
    for (int mi = 0; mi < MR; ++mi)
#pragma unroll
        for (int ni = 0; ni < NR; ++ni)
            acc[mi][ni] = (floatx4){0.f, 0.f, 0.f, 0.f};

    for (int k0 = 0; k0 < K; k0 += BK) {
#pragma unroll
        for (int r = 0; r < BM / 64; ++r)
            __builtin_amdgcn_global_load_lds(
                (const GLB unsigned int*)&A[(size_t)(m0 + r * 64 + srow) * lda + k0 + scol],
                (LDS unsigned int*)&Alds[r * 2048 + tid * 8], 16, 0, 0);
#pragma unroll
        for (int r = 0; r < BN / 64; ++r)
            __builtin_amdgcn_global_load_lds(
                (const GLB unsigned int*)&B[(size_t)(n0 + r * 64 + srow) * ldb + k0 + scol],
                (LDS unsigned int*)&Blds[r * 2048 + tid * 8], 16, 0, 0);
        __syncthreads();

        short8 af[MR], bf[NR];
#pragma unroll
        for (int mi = 0; mi < MR; ++mi)
            af[mi] = *reinterpret_cast<const short8*>(
                &Alds[(wm * (BM / 2) + mi * 16 + fr) * BK + kg * 8]);
#pragma unroll
        for (int ni = 0; ni < NR; ++ni)
            bf[ni] = *reinterpret_cast<const short8*>(
                &Blds[(wn * (BN / 2) + ni * 16 + fr) * BK + kg * 8]);
#pragma unroll
        for (int mi = 0; mi < MR; ++mi)
#pragma unroll
            for (int ni = 0; ni < NR; ++ni)
                acc[mi][ni] = __builtin_amdgcn_mfma_f32_16x16x32_bf16(
                    af[mi], bf[ni], acc[mi][ni], 0, 0, 0);
        __syncthreads();
    }

#pragma unroll
    for (int mi = 0; mi < MR; ++mi)
#pragma unroll
        for (int ni = 0; ni < NR; ++ni)
#pragma unroll
            for (int r = 0; r < 4; ++r) {
                int row = m0 + wm * (BM / 2) + mi * 16 + kg * 4 + r;
                int col = n0 + wn * (BN / 2) + ni * 16 + fr;
                float v = acc[mi][ni][r];
                if constexpr (EPI == 1) {
                    v += bias[col];
                    v = (v > 20.f) ? v : log1pf(__expf(v));
                }
                if constexpr (sizeof(OutT) == 2)
                    C[(size_t)row * ldc + col] = (OutT)f2b(v);
                else
                    C[(size_t)row * ldc + col] = v;
            }
}

// causal depthwise conv (width 4) + bias + silu; xi = xz[:, 0:2048]; out bf16.
__global__ __launch_bounds__(256)
void conv_silu(const float* __restrict__ xz,
               const float* __restrict__ conv_w,
               const float* __restrict__ conv_b,
               unsigned short* __restrict__ xic)
{
    int idx = blockIdx.x * 256 + threadIdx.x;   // over SEQ*DINNER
    int l = idx / DINNER;
    int d = idx % DINNER;
    float acc = conv_b[d];
    float4 w = *reinterpret_cast<const float4*>(&conv_w[d * 4]);
    float wk[4] = {w.x, w.y, w.z, w.w};
#pragma unroll
    for (int k = 0; k < 4; ++k) {
        int ls = l - 3 + k;
        if (ls >= 0) acc = fmaf(xz[(size_t)ls * (2 * DINNER) + d], wk[k], acc);
    }
    xic[idx] = f2b(siluf(acc));
}

// ---------------- chunk-parallel selective scan ----------------
__global__ __launch_bounds__(256)
void scan_pass1(const float* __restrict__ delta,
                const unsigned short* __restrict__ xic,
                const unsigned short* __restrict__ xdbl,   // bf16, ld XPWP
                const float* __restrict__ A_log,
                float* __restrict__ Pbuf, float* __restrict__ Sbuf)
{
    const int tid = threadIdx.x;
    const int n   = tid & 15;
    const int dd  = tid >> 4;
    const int d0  = blockIdx.x * 16;
    const int d   = d0 + dd;
    const int c   = blockIdx.y;
    const int tb  = c * CH;

    const float Aneg = -__expf(A_log[d * DSTATE + n]);
    float h = 0.f, sdl = 0.f;

    __shared__ float ds[16][16], xs[16][16], Bsh[16][16];
    const int lr = tid >> 4, lc = tid & 15;

    for (int t0 = 0; t0 < CH; t0 += 16) {
        int t = tb + t0 + lr;
        ds[lr][lc]  = delta[(size_t)t * DINNER + d0 + lc];
        xs[lr][lc]  = b2f(xic[(size_t)t * DINNER + d0 + lc]);
        Bsh[lr][lc] = b2f(xdbl[(size_t)t * XPWP + DTRANK + lc]);
        __syncthreads();
#pragma unroll
        for (int tt = 0; tt < 16; ++tt) {
            float dl = ds[tt][dd];
            float xv = xs[tt][dd];
            float a  = __expf(dl * Aneg);
            h = fmaf(a, h, dl * xv * Bsh[tt][n]);
            sdl += dl;
        }
        __syncthreads();
    }
    size_t o = ((size_t)c * DINNER + d) * 16 + n;
    Pbuf[o] = __expf(sdl * Aneg);
    Sbuf[o] = h;
}

__global__ __launch_bounds__(256)
void scan_pass2(const float* __restrict__ Pbuf,
                const float* __restrict__ Sbuf,
                float* __restrict__ Hin)
{
    int idx = blockIdx.x * 256 + threadIdx.x;   // over DINNER*16
    float h = 0.f;
#pragma unroll
    for (int c = 0; c < NC; ++c) {
        size_t o = (size_t)c * (DINNER * DSTATE) + idx;
        Hin[o] = h;
        h = fmaf(Pbuf[o], h, Sbuf[o]);
    }
}

__global__ __launch_bounds__(256)
void scan_pass3(const float* __restrict__ delta,
                const unsigned short* __restrict__ xic,
                const unsigned short* __restrict__ xdbl,
                const float* __restrict__ A_log,
                const float* __restrict__ D_skip,
                const float* __restrict__ xz,      // z at [:, 2048:]
                const float* __restrict__ Hin,
                unsigned short* __restrict__ yfin) // bf16 out
{
    const int tid = threadIdx.x;
    const int n   = tid & 15;
    const int dd  = tid >> 4;
    const int d0  = blockIdx.x * 16;
    const int d   = d0 + dd;
    const int c   = blockIdx.y;
    const int tb  = c * CH;

    const float Aneg = -__expf(A_log[d * DSTATE + n]);
    float h = Hin[((size_t)c * DINNER + d) * 16 + n];

    __shared__ float ds[16][16], xs[16][16], Bsh[16][16], Csh[16][16], ys[16][17];
    const int lr = tid >> 4, lc = tid & 15;

    for (int t0 = 0; t0 < CH; t0 += 16) {
        int t = tb + t0 + lr;
        ds[lr][lc]  = delta[(size_t)t * DINNER + d0 + lc];
        xs[lr][lc]  = b2f(xic[(size_t)t * DINNER + d0 + lc]);
        Bsh[lr][lc] = b2f(xdbl[(size_t)t * XPWP + DTRANK + lc]);
        Csh[lr][lc] = b2f(xdbl[(size_t)t * XPWP + DTRANK + DSTATE + lc]);
        __syncthreads();
#pragma unroll
        for (int tt = 0; tt < 16; ++tt) {
            float dl = ds[tt][dd];
            float xv = xs[tt][dd];
            float a  = __expf(dl * Aneg);
            h = fmaf(a, h, dl * xv * Bsh[tt][n]);
            float py = h * Csh[tt][n];
            py += __shfl_xor(py, 1);
            py += __shfl_xor(py, 2);
            py += __shfl_xor(py, 4);
            py += __shfl_xor(py, 8);
            if (n == 0) ys[tt][dd] = py;
        }
        __syncthreads();
        {
            int t2 = tb + t0 + lr;
            int dg = d0 + lc;
            float yv  = ys[lr][lc];
            float xiv = xs[lr][lc];
            float zv  = xz[(size_t)t2 * (2 * DINNER) + DINNER + dg];
            yfin[(size_t)t2 * DINNER + dg] = f2b(fmaf(xiv, D_skip[dg], yv) * siluf(zv));
        }
        __syncthreads();
    }
}

}  // namespace

extern "C" void kernel_launch(void* const* d_in, const int* in_sizes, int n_in,
                              void* d_out, int out_size, void* d_ws, size_t ws_size,
                              hipStream_t stream)
{
    (void)in_sizes; (void)n_in; (void)out_size; (void)ws_size;

    const float* x       = (const float*)d_in[0];
    const float* W_in    = (const float*)d_in[1];
    const float* conv_w  = (const float*)d_in[2];
    const float* conv_b  = (const float*)d_in[3];
    const float* W_xproj = (const float*)d_in[4];
    const float* W_dt    = (const float*)d_in[5];
    const float* b_dt    = (const float*)d_in[6];
    const float* A_log   = (const float*)d_in[7];
    const float* D_skip  = (const float*)d_in[8];
    const float* W_out   = (const float*)d_in[9];
    float* out = (float*)d_out;

    // ---- workspace carve (f32 region then bf16 region) ----
    float* ws    = (float*)d_ws;
    float* xz    = ws;                                   // SEQ*4096 f32
    float* delta = xz    + (size_t)SEQ * 2 * DINNER;     // SEQ*2048 f32
    float* Pbuf  = delta + (size_t)SEQ * DINNER;         // NC*DINNER*16
    float* Sbuf  = Pbuf  + (size_t)NC * DINNER * DSTATE;
    float* Hin   = Sbuf  + (size_t)NC * DINNER * DSTATE;
    unsigned short* us   = (unsigned short*)(Hin + (size_t)NC * DINNER * DSTATE);
    unsigned short* x_b    = us;                                   // 1M
    unsigned short* Win_b  = x_b   + (size_t)SEQ * DMODEL;         // 4.19M
    unsigned short* Wxp_b  = Win_b + (size_t)2 * DINNER * DMODEL;  // 128*2048
    unsigned short* Wdt_b  = Wxp_b + (size_t)XPWP * DINNER;        // 2048*64
    unsigned short* Wout_b = Wdt_b + (size_t)DINNER * DTRANK;      // 1024*2048
    unsigned short* xic_b  = Wout_b + (size_t)DMODEL * DINNER;     // SEQ*2048
    unsigned short* xdbl_b = xic_b  + (size_t)SEQ * DINNER;        // SEQ*128
    unsigned short* yfin_b = xdbl_b + (size_t)SEQ * XPWP;          // SEQ*2048

    // ---- 0) casts to bf16 ----
    cast_bf16<<<(SEQ * DMODEL) / 2048, 256, 0, stream>>>(x, x_b);
    cast_bf16<<<(2 * DINNER * DMODEL) / 2048, 256, 0, stream>>>(W_in, Win_b);
    cast_pad_xproj<<<(XPWP * DINNER) / 2048, 256, 0, stream>>>(W_xproj, Wxp_b);
    cast_bf16<<<(DINNER * DTRANK) / 2048, 256, 0, stream>>>(W_dt, Wdt_b);
    cast_bf16<<<(DMODEL * DINNER) / 2048, 256, 0, stream>>>(W_out, Wout_b);

    // ---- 1) xz = x @ W_in^T   (1024 x 4096, K=1024) ----
    gemm_mfma<128, 128, 0, float><<<dim3(4096 / 128, SEQ / 128), 256, 0, stream>>>(
        x_b, DMODEL, Win_b, DMODEL, xz, 2 * DINNER, nullptr, DMODEL);

    // ---- 2) conv + silu -> xic (bf16) ----
    conv_silu<<<(SEQ * DINNER) / 256, 256, 0, stream>>>(xz, conv_w, conv_b, xic_b);

    // ---- 3) x_dbl = xic @ W_xproj^T  (1024 x 128pad, K=2048) -> bf16 ----
    gemm_mfma<128, 128, 2, unsigned short><<<dim3(1, SEQ / 128), 256, 0, stream>>>(
        xic_b, DINNER, Wxp_b, DINNER, xdbl_b, XPWP, nullptr, DINNER);

    // ---- 4) delta = softplus(dt @ W_dt^T + b_dt)  (1024 x 2048, K=64) ----
    gemm_mfma<128, 128, 1, float><<<dim3(DINNER / 128, SEQ / 128), 256, 0, stream>>>(
        xdbl_b, XPWP, Wdt_b, DTRANK, delta, DINNER, b_dt, DTRANK);

    // ---- 5) chunk-parallel selective scan + gate fusion ----
    scan_pass1<<<dim3(DINNER / 16, NC), 256, 0, stream>>>(
        delta, xic_b, xdbl_b, A_log, Pbuf, Sbuf);
    scan_pass2<<<(DINNER * DSTATE) / 256, 256, 0, stream>>>(Pbuf, Sbuf, Hin);
    scan_pass3<<<dim3(DINNER / 16, NC), 256, 0, stream>>>(
        delta, xic_b, xdbl_b, A_log, D_skip, xz, Hin, yfin_b);

    // ---- 6) out = y @ W_out^T  (1024 x 1024, K=2048) ----
    gemm_mfma<128, 128, 0, float><<<dim3(DMODEL / 128, SEQ / 128), 256, 0, stream>>>(
        yfin_b, DINNER, Wout_b, DINNER, out, DMODEL, nullptr, DINNER);
}

// Round 4
// 178.104 us; speedup vs baseline: 3.1238x; 1.2412x over previous
//
#include <hip/hip_runtime.h>
#include <hip/hip_bf16.h>
#include <math.h>

namespace {

constexpr int SEQ    = 1024;
constexpr int DMODEL = 1024;
constexpr int DINNER = 2048;
constexpr int DSTATE = 16;
constexpr int DTRANK = 64;
constexpr int XPW    = 96;
constexpr int XPWP   = 128;

typedef __attribute__((ext_vector_type(8))) short short8;
typedef __attribute__((ext_vector_type(4))) short short4_t;
typedef __attribute__((ext_vector_type(4))) float floatx4;

#define GLB __attribute__((address_space(1)))
#define LDSAS __attribute__((address_space(3)))

__device__ __forceinline__ float siluf(float x) { return x / (1.f + __expf(-x)); }

__device__ __forceinline__ unsigned short f2b(float f) {
    __hip_bfloat16 h = __float2bfloat16(f);
    return *reinterpret_cast<unsigned short*>(&h);
}
__device__ __forceinline__ float b2f(unsigned short u) {
    union { unsigned int i; float f; } v; v.i = (unsigned int)u << 16; return v.f;
}

// ---------------- fused bf16 cast of x + all weights (one launch) ----------------
constexpr size_t N_XB   = (size_t)SEQ * DMODEL;        // 1048576
constexpr size_t N_WIN  = (size_t)2 * DINNER * DMODEL; // 4194304
constexpr size_t N_WXP  = (size_t)XPWP * DINNER;       // 262144 (padded)
constexpr size_t N_WDT  = (size_t)DINNER * DTRANK;     // 131072
constexpr size_t N_WOUT = (size_t)DMODEL * DINNER;     // 2097152
constexpr size_t CO1 = N_XB, CO2 = CO1 + N_WIN, CO3 = CO2 + N_WXP,
                 CO4 = CO3 + N_WDT, CO5 = CO4 + N_WOUT;          // 7733248

__global__ __launch_bounds__(256)
void cast_all(const float* __restrict__ x, const float* __restrict__ Win,
              const float* __restrict__ Wxp, const float* __restrict__ Wdt,
              const float* __restrict__ Wout, unsigned short* __restrict__ dst)
{
    size_t i = ((size_t)blockIdx.x * 256 + threadIdx.x) * 8;
    if (i >= CO5) return;
    const float* src; size_t si;
    if (i < CO1)      { src = x;   si = i; }
    else if (i < CO2) { src = Win; si = i - CO1; }
    else if (i < CO3) {
        size_t j = i - CO2, row = j / DINNER;
        if (row >= XPW) { short8 z = {0,0,0,0,0,0,0,0};
                          *reinterpret_cast<short8*>(&dst[i]) = z; return; }
        src = Wxp; si = j;
    }
    else if (i < CO4) { src = Wdt;  si = i - CO3; }
    else              { src = Wout; si = i - CO4; }
    float4 a = *reinterpret_cast<const float4*>(&src[si]);
    float4 b = *reinterpret_cast<const float4*>(&src[si + 4]);
    short8 o;
    o[0]=(short)f2b(a.x); o[1]=(short)f2b(a.y); o[2]=(short)f2b(a.z); o[3]=(short)f2b(a.w);
    o[4]=(short)f2b(b.x); o[5]=(short)f2b(b.y); o[6]=(short)f2b(b.z); o[7]=(short)f2b(b.w);
    *reinterpret_cast<short8*>(&dst[i]) = o;
}

// ---------------- bf16 MFMA GEMM, 128x128 tile, 2-phase prefetch dbuf ----------------
// C[M][N] = A[M][K] @ B[N][K]^T.  Optional split-K via blockIdx.z (partial slabs).
// EPI: 0 = f32 store, 1 = softplus(v + bias[n]) f32 store.
template<int EPI>
__global__ __launch_bounds__(256)
void gemm_mfma(const unsigned short* __restrict__ A, int lda,
               const unsigned short* __restrict__ B, int ldb,
               float* __restrict__ C, int ldc, size_t czstride,
               const float* __restrict__ bias, int Ksub)
{
    constexpr int BM = 128, BN = 128, BK = 32, MR = 4, NR = 4;
    __shared__ unsigned short Alds[2][BM * BK];
    __shared__ unsigned short Blds[2][BN * BK];

    const int tid  = threadIdx.x;
    const int lane = tid & 63;
    const int wv   = tid >> 6;
    const int wm   = wv >> 1, wn = wv & 1;
    const int fr   = lane & 15;
    const int kg   = lane >> 4;
    const int m0   = blockIdx.y * BM;
    const int n0   = blockIdx.x * BN;
    const int kb   = blockIdx.z * Ksub;
    const int srow = tid >> 2;
    const int scol = (tid & 3) * 8;
    float* Cz = C + (size_t)blockIdx.z * czstride;

    floatx4 acc[MR][NR];
#pragma unroll
    for (int mi = 0; mi < MR; ++mi)
#pragma unroll
        for (int ni = 0; ni < NR; ++ni)
            acc[mi][ni] = (floatx4){0.f, 0.f, 0.f, 0.f};

    auto stage = [&](int buf, int k0) {
#pragma unroll
        for (int r = 0; r < 2; ++r)
            __builtin_amdgcn_global_load_lds(
                (const GLB unsigned int*)&A[(size_t)(m0 + r * 64 + srow) * lda + k0 + scol],
                (LDSAS unsigned int*)&Alds[buf][r * 2048 + tid * 8], 16, 0, 0);
#pragma unroll
        for (int r = 0; r < 2; ++r)
            __builtin_amdgcn_global_load_lds(
                (const GLB unsigned int*)&B[(size_t)(n0 + r * 64 + srow) * ldb + k0 + scol],
                (LDSAS unsigned int*)&Blds[buf][r * 2048 + tid * 8], 16, 0, 0);
    };

    const int nt = Ksub / BK;
    stage(0, kb);
    __syncthreads();                  // vmcnt(0) drain + barrier: buf0 ready
    int cur = 0;
    for (int t = 0; t < nt; ++t) {
        if (t + 1 < nt) stage(cur ^ 1, kb + (t + 1) * BK);   // prefetch next
        short8 af[MR], bf[NR];
#pragma unroll
        for (int mi = 0; mi < MR; ++mi)
            af[mi] = *reinterpret_cast<const short8*>(
                &Alds[cur][(wm * 64 + mi * 16 + fr) * BK + kg * 8]);
#pragma unroll
        for (int ni = 0; ni < NR; ++ni)
            bf[ni] = *reinterpret_cast<const short8*>(
                &Blds[cur][(wn * 64 + ni * 16 + fr) * BK + kg * 8]);
#pragma unroll
        for (int mi = 0; mi < MR; ++mi)
#pragma unroll
            for (int ni = 0; ni < NR; ++ni)
                acc[mi][ni] = __builtin_amdgcn_mfma_f32_16x16x32_bf16(
                    af[mi], bf[ni], acc[mi][ni], 0, 0, 0);
        __syncthreads();              // prefetch landed + all reads of cur retired
        cur ^= 1;
    }

#pragma unroll
    for (int mi = 0; mi < MR; ++mi)
#pragma unroll
        for (int ni = 0; ni < NR; ++ni)
#pragma unroll
            for (int r = 0; r < 4; ++r) {
                int row = m0 + wm * 64 + mi * 16 + kg * 4 + r;
                int col = n0 + wn * 64 + ni * 16 + fr;
                float v = acc[mi][ni][r];
                if constexpr (EPI == 1) {
                    v += bias[col];
                    v = (v > 20.f) ? v : log1pf(__expf(v));
                }
                Cz[(size_t)row * ldc + col] = v;
            }
}

// sum 4 split-K partials -> xdbl f32 + bf16
__global__ __launch_bounds__(256)
void combine_xdbl(const float* __restrict__ xp, float* __restrict__ xf,
                  unsigned short* __restrict__ xb)
{
    int i = (blockIdx.x * 256 + threadIdx.x) * 4;   // over SEQ*XPWP = 131072
    constexpr size_t SL = (size_t)SEQ * XPWP;
    float4 s0 = *reinterpret_cast<const float4*>(&xp[i]);
    float4 s1 = *reinterpret_cast<const float4*>(&xp[SL + i]);
    float4 s2 = *reinterpret_cast<const float4*>(&xp[2 * SL + i]);
    float4 s3 = *reinterpret_cast<const float4*>(&xp[3 * SL + i]);
    float4 s{ s0.x+s1.x+s2.x+s3.x, s0.y+s1.y+s2.y+s3.y,
              s0.z+s1.z+s2.z+s3.z, s0.w+s1.w+s2.w+s3.w };
    *reinterpret_cast<float4*>(&xf[i]) = s;
    short4_t o; o[0]=(short)f2b(s.x); o[1]=(short)f2b(s.y);
                o[2]=(short)f2b(s.z); o[3]=(short)f2b(s.w);
    *reinterpret_cast<short4_t*>(&xb[i]) = o;
}

// causal depthwise conv (width 4) + bias + silu; xi = xz[:, 0:2048]; out bf16.
__global__ __launch_bounds__(256)
void conv_silu(const float* __restrict__ xz,
               const float* __restrict__ conv_w,
               const float* __restrict__ conv_b,
               unsigned short* __restrict__ xic)
{
    int idx = blockIdx.x * 256 + threadIdx.x;
    int l = idx / DINNER;
    int d = idx % DINNER;
    float acc = conv_b[d];
    float4 w = *reinterpret_cast<const float4*>(&conv_w[d * 4]);
    float wk[4] = {w.x, w.y, w.z, w.w};
#pragma unroll
    for (int k = 0; k < 4; ++k) {
        int ls = l - 3 + k;
        if (ls >= 0) acc = fmaf(xz[(size_t)ls * (2 * DINNER) + d], wk[k], acc);
    }
    xic[idx] = f2b(siluf(acc));
}

// ---------------- chunk-parallel selective scan, n-in-registers ----------------
// lane owns one d; 16 h[n] states in VGPRs; B/C broadcast from LDS.
// Summary layout: [c][n][d] so every global access is lane-coalesced.

__global__ __launch_bounds__(256)
void scan_pass1(const float* __restrict__ delta,
                const unsigned short* __restrict__ xic,
                const float* __restrict__ xdbl,     // f32 [SEQ][128], B at 64
                const float* __restrict__ A_log,
                float* __restrict__ Pbuf, float* __restrict__ Sbuf, int CH)
{
    const int tid = threadIdx.x;
    const int d   = blockIdx.x * 256 + tid;
    const int c   = blockIdx.y;
    const int tb  = c * CH;

    float An[16], h[16];
#pragma unroll
    for (int n = 0; n < 16; ++n) {
        An[n] = -__expf(A_log[(size_t)d * 16 + n]);
        h[n]  = 0.f;
    }
    float sdl = 0.f;

    __shared__ float Bls[16][16];
    const int sr = tid >> 4, sq = tid & 15;

    for (int s0 = 0; s0 < CH; s0 += 16) {
        Bls[sr][sq] = xdbl[(size_t)(tb + s0 + sr) * XPWP + DTRANK + sq];
        __syncthreads();
#pragma unroll
        for (int tt = 0; tt < 16; ++tt) {
            int t = tb + s0 + tt;
            float dl = delta[(size_t)t * DINNER + d];
            float xv = b2f(xic[(size_t)t * DINNER + d]);
            float t1 = dl * xv;
            sdl += dl;
            floatx4 B0 = *reinterpret_cast<const floatx4*>(&Bls[tt][0]);
            floatx4 B1 = *reinterpret_cast<const floatx4*>(&Bls[tt][4]);
            floatx4 B2 = *reinterpret_cast<const floatx4*>(&Bls[tt][8]);
            floatx4 B3 = *reinterpret_cast<const floatx4*>(&Bls[tt][12]);
#pragma unroll
            for (int n = 0; n < 16; ++n) {
                float bn = (n < 4) ? B0[n] : (n < 8) ? B1[n-4] : (n < 12) ? B2[n-8] : B3[n-12];
                float a  = __expf(dl * An[n]);
                h[n] = fmaf(a, h[n], t1 * bn);
            }
        }
        __syncthreads();
    }
#pragma unroll
    for (int n = 0; n < 16; ++n) {
        size_t o = ((size_t)c * 16 + n) * DINNER + d;
        Pbuf[o] = __expf(sdl * An[n]);
        Sbuf[o] = h[n];
    }
}

// serial scan over chunk summaries; Hin written in place over Sbuf
__global__ __launch_bounds__(256)
void scan_pass2(const float* __restrict__ Pbuf, float* __restrict__ Sbuf, int NCr)
{
    int idx = blockIdx.x * 256 + threadIdx.x;   // over DINNER*16 = 32768 (n*2048+d)
    float h = 0.f;
    for (int c = 0; c < NCr; ++c) {
        size_t o = (size_t)c * (DINNER * DSTATE) + idx;
        float p = Pbuf[o], s = Sbuf[o];
        Sbuf[o] = h;                 // Hin for chunk c
        h = fmaf(p, h, s);
    }
}

__global__ __launch_bounds__(256)
void scan_pass3(const float* __restrict__ delta,
                const unsigned short* __restrict__ xic,
                const float* __restrict__ xdbl,     // B at 64, C at 80 (f32)
                const float* __restrict__ A_log,
                const float* __restrict__ D_skip,
                const float* __restrict__ xz,       // z at [:, 2048:]
                const float* __restrict__ Hin,      // [c][n][d] (= Sbuf)
                unsigned short* __restrict__ yfin, int CH)
{
    const int tid = threadIdx.x;
    const int d   = blockIdx.x * 256 + tid;
    const int c   = blockIdx.y;
    const int tb  = c * CH;

    float An[16], h[16];
#pragma unroll
    for (int n = 0; n < 16; ++n) {
        An[n] = -__expf(A_log[(size_t)d * 16 + n]);
        h[n]  = Hin[((size_t)c * 16 + n) * DINNER + d];
    }
    const float Dsk = D_skip[d];

    __shared__ float Bls[16][32];                   // [t][B0..15,C0..15]
    const int sr = tid >> 4, sq = (tid & 15) * 2;

    for (int s0 = 0; s0 < CH; s0 += 16) {
        float2 bc = *reinterpret_cast<const float2*>(
            &xdbl[(size_t)(tb + s0 + sr) * XPWP + DTRANK + sq]);
        Bls[sr][sq] = bc.x; Bls[sr][sq + 1] = bc.y;
        __syncthreads();
#pragma unroll
        for (int tt = 0; tt < 16; ++tt) {
            int t = tb + s0 + tt;
            float dl = delta[(size_t)t * DINNER + d];
            float xv = b2f(xic[(size_t)t * DINNER + d]);
            float zv = xz[(size_t)t * (2 * DINNER) + DINNER + d];
            float t1 = dl * xv;
            floatx4 B0 = *reinterpret_cast<const floatx4*>(&Bls[tt][0]);
            floatx4 B1 = *reinterpret_cast<const floatx4*>(&Bls[tt][4]);
            floatx4 B2 = *reinterpret_cast<const floatx4*>(&Bls[tt][8]);
            floatx4 B3 = *reinterpret_cast<const floatx4*>(&Bls[tt][12]);
            floatx4 C0 = *reinterpret_cast<const floatx4*>(&Bls[tt][16]);
            floatx4 C1 = *reinterpret_cast<const floatx4*>(&Bls[tt][20]);
            floatx4 C2 = *reinterpret_cast<const floatx4*>(&Bls[tt][24]);
            floatx4 C3 = *reinterpret_cast<const floatx4*>(&Bls[tt][28]);
            float y = 0.f;
#pragma unroll
            for (int n = 0; n < 16; ++n) {
                float bn = (n < 4) ? B0[n] : (n < 8) ? B1[n-4] : (n < 12) ? B2[n-8] : B3[n-12];
                float cn = (n < 4) ? C0[n] : (n < 8) ? C1[n-4] : (n < 12) ? C2[n-8] : C3[n-12];
                float a  = __expf(dl * An[n]);
                h[n] = fmaf(a, h[n], t1 * bn);
                y = fmaf(h[n], cn, y);
            }
            float yv = fmaf(xv, Dsk, y) * siluf(zv);
            yfin[(size_t)t * DINNER + d] = f2b(yv);
        }
        __syncthreads();
    }
}

}  // namespace

extern "C" void kernel_launch(void* const* d_in, const int* in_sizes, int n_in,
                              void* d_out, int out_size, void* d_ws, size_t ws_size,
                              hipStream_t stream)
{
    (void)in_sizes; (void)n_in; (void)out_size;

    const float* x       = (const float*)d_in[0];
    const float* W_in    = (const float*)d_in[1];
    const float* conv_w  = (const float*)d_in[2];
    const float* conv_b  = (const float*)d_in[3];
    const float* W_xproj = (const float*)d_in[4];
    const float* W_dt    = (const float*)d_in[5];
    const float* b_dt    = (const float*)d_in[6];
    const float* A_log   = (const float*)d_in[7];
    const float* D_skip  = (const float*)d_in[8];
    const float* W_out   = (const float*)d_in[9];
    float* out = (float*)d_out;

    // ---- pick NC by workspace budget ----
    const size_t BF16_SHORTS = CO5 + (size_t)SEQ * DINNER + (size_t)SEQ * XPWP
                             + (size_t)SEQ * DINNER;                 // casts + xic + xdbl_b + yfin
    const size_t F32_FIXED   = (size_t)SEQ * 2 * DINNER + (size_t)SEQ * DINNER
                             + (size_t)SEQ * XPWP + 4 * (size_t)SEQ * XPWP; // xz, delta, xdbl_f, xpart
    auto need = [&](int nc) {
        return (F32_FIXED + 2 * (size_t)nc * DINNER * DSTATE) * 4 + BF16_SHORTS * 2;
    };
    int NC = 64;
    if (need(64) > ws_size) NC = 32;
    if (need(32) > ws_size) NC = 16;
    const int CH = SEQ / NC;

    // ---- workspace carve: f32 region, then bf16 region ----
    float* ws     = (float*)d_ws;
    float* xz     = ws;                                   // SEQ*4096
    float* delta  = xz    + (size_t)SEQ * 2 * DINNER;     // SEQ*2048
    float* xdbl_f = delta + (size_t)SEQ * DINNER;         // SEQ*128
    float* xpart  = xdbl_f + (size_t)SEQ * XPWP;          // 4*SEQ*128
    float* Pbuf   = xpart + 4 * (size_t)SEQ * XPWP;       // NC*16*2048
    float* Sbuf   = Pbuf  + (size_t)NC * DINNER * DSTATE; // NC*16*2048 (also Hin)
    unsigned short* us     = (unsigned short*)(Sbuf + (size_t)NC * DINNER * DSTATE);
    unsigned short* x_b    = us;                      // cast_all region, CO5 shorts
    unsigned short* Win_b  = x_b + CO1;
    unsigned short* Wxp_b  = x_b + CO2;
    unsigned short* Wdt_b  = x_b + CO3;
    unsigned short* Wout_b = x_b + CO4;
    unsigned short* xic_b  = x_b + CO5;
    unsigned short* xdbl_b = xic_b + (size_t)SEQ * DINNER;
    unsigned short* yfin_b = xdbl_b + (size_t)SEQ * XPWP;

    // 0) all bf16 casts in one launch
    cast_all<<<(int)((CO5 / 8 + 255) / 256), 256, 0, stream>>>(
        x, W_in, W_xproj, W_dt, W_out, x_b);

    // 1) xz = x @ W_in^T   (1024 x 4096, K=1024)
    gemm_mfma<0><<<dim3(4096 / 128, SEQ / 128, 1), 256, 0, stream>>>(
        x_b, DMODEL, Win_b, DMODEL, xz, 2 * DINNER, 0, nullptr, DMODEL);

    // 2) conv + silu -> xic (bf16)
    conv_silu<<<(SEQ * DINNER) / 256, 256, 0, stream>>>(xz, conv_w, conv_b, xic_b);

    // 3) x_dbl = xic @ W_xproj^T, split-K=4 partials (1024 x 128, K=2048)
    gemm_mfma<0><<<dim3(1, SEQ / 128, 4), 256, 0, stream>>>(
        xic_b, DINNER, Wxp_b, DINNER, xpart, XPWP, (size_t)SEQ * XPWP, nullptr, DINNER / 4);
    combine_xdbl<<<(SEQ * XPWP) / 1024, 256, 0, stream>>>(xpart, xdbl_f, xdbl_b);

    // 4) delta = softplus(dt @ W_dt^T + b_dt)  (1024 x 2048, K=64)
    gemm_mfma<1><<<dim3(DINNER / 128, SEQ / 128, 1), 256, 0, stream>>>(
        xdbl_b, XPWP, Wdt_b, DTRANK, delta, DINNER, 0, b_dt, DTRANK);

    // 5) chunk-parallel selective scan + gate fusion
    scan_pass1<<<dim3(DINNER / 256, NC), 256, 0, stream>>>(
        delta, xic_b, xdbl_f, A_log, Pbuf, Sbuf, CH);
    scan_pass2<<<(DINNER * DSTATE) / 256, 256, 0, stream>>>(Pbuf, Sbuf, NC);
    scan_pass3<<<dim3(DINNER / 256, NC), 256, 0, stream>>>(
        delta, xic_b, xdbl_f, A_log, D_skip, xz, Sbuf, yfin_b, CH);

    // 6) out = y @ W_out^T  (1024 x 1024, K=2048)
    gemm_mfma<0><<<dim3(DMODEL / 128, SEQ / 128, 1), 256, 0, stream>>>(
        yfin_b, DINNER, Wout_b, DINNER, out, DMODEL, 0, nullptr, DINNER);
}

// Round 5
// 136.708 us; speedup vs baseline: 4.0697x; 1.3028x over previous
//
#include <hip/hip_runtime.h>
#include <hip/hip_bf16.h>
#include <math.h>

namespace {

constexpr int SEQ    = 1024;
constexpr int DMODEL = 1024;
constexpr int DINNER = 2048;
constexpr int DSTATE = 16;
constexpr int DTRANK = 64;
constexpr int XPW    = 96;
constexpr int XPWP   = 128;

typedef __attribute__((ext_vector_type(8))) short short8;
typedef __attribute__((ext_vector_type(4))) short short4_t;
typedef __attribute__((ext_vector_type(4))) float floatx4;

#define GLB __attribute__((address_space(1)))
#define LDSAS __attribute__((address_space(3)))

__device__ __forceinline__ float siluf(float x) { return x / (1.f + __expf(-x)); }

__device__ __forceinline__ unsigned short f2b(float f) {
    __hip_bfloat16 h = __float2bfloat16(f);
    return *reinterpret_cast<unsigned short*>(&h);
}
__device__ __forceinline__ float b2f(unsigned short u) {
    union { unsigned int i; float f; } v; v.i = (unsigned int)u << 16; return v.f;
}

// ---------------- fused bf16 cast of x + all weights ----------------
constexpr size_t N_XB   = (size_t)SEQ * DMODEL;
constexpr size_t N_WIN  = (size_t)2 * DINNER * DMODEL;
constexpr size_t N_WXP  = (size_t)XPWP * DINNER;
constexpr size_t N_WDT  = (size_t)DINNER * DTRANK;
constexpr size_t N_WOUT = (size_t)DMODEL * DINNER;
constexpr size_t CO1 = N_XB, CO2 = CO1 + N_WIN, CO3 = CO2 + N_WXP,
                 CO4 = CO3 + N_WDT, CO5 = CO4 + N_WOUT;

__global__ __launch_bounds__(256)
void cast_all(const float* __restrict__ x, const float* __restrict__ Win,
              const float* __restrict__ Wxp, const float* __restrict__ Wdt,
              const float* __restrict__ Wout, unsigned short* __restrict__ dst)
{
    size_t i = ((size_t)blockIdx.x * 256 + threadIdx.x) * 8;
    if (i >= CO5) return;
    const float* src; size_t si;
    if (i < CO1)      { src = x;   si = i; }
    else if (i < CO2) { src = Win; si = i - CO1; }
    else if (i < CO3) {
        size_t j = i - CO2, row = j / DINNER;
        if (row >= XPW) { short8 z = {0,0,0,0,0,0,0,0};
                          *reinterpret_cast<short8*>(&dst[i]) = z; return; }
        src = Wxp; si = j;
    }
    else if (i < CO4) { src = Wdt;  si = i - CO3; }
    else              { src = Wout; si = i - CO4; }
    float4 a = *reinterpret_cast<const float4*>(&src[si]);
    float4 b = *reinterpret_cast<const float4*>(&src[si + 4]);
    short8 o;
    o[0]=(short)f2b(a.x); o[1]=(short)f2b(a.y); o[2]=(short)f2b(a.z); o[3]=(short)f2b(a.w);
    o[4]=(short)f2b(b.x); o[5]=(short)f2b(b.y); o[6]=(short)f2b(b.z); o[7]=(short)f2b(b.w);
    *reinterpret_cast<short8*>(&dst[i]) = o;
}

// ---------------- bf16 MFMA GEMM, 64x128 tile, 2-phase dbuf, XCD swizzle --------
// C[M][N] = A[M][K] @ B[N][K]^T.  1D grid (nbx*nby) in x, split-K in z.
// Waves 2x2: each wave owns 32x64 (MR=2 x NR=4 frags of 16x16x32).
// EPI: 0 = f32 store, 1 = softplus(v + bias[n]) f32 store.
template<int EPI>
__global__ __launch_bounds__(256)
void gemm_mfma(const unsigned short* __restrict__ A, int lda,
               const unsigned short* __restrict__ B, int ldb,
               float* __restrict__ C, int ldc, size_t czstride,
               const float* __restrict__ bias, int Ksub, int nbx)
{
    constexpr int BM = 64, BN = 128, BK = 32, MR = 2, NR = 4;
    __shared__ unsigned short Alds[2][BM * BK];
    __shared__ unsigned short Blds[2][BN * BK];

    // bijective XCD-chunk swizzle (nwg % 8 == 0 for all our launches)
    const int nwg = gridDim.x;
    int id = blockIdx.x;
    int wg = ((nwg & 7) == 0) ? (id & 7) * (nwg >> 3) + (id >> 3) : id;
    const int bx = wg % nbx, by = wg / nbx;

    const int tid  = threadIdx.x;
    const int lane = tid & 63;
    const int wv   = tid >> 6;
    const int wm   = wv >> 1, wn = wv & 1;
    const int fr   = lane & 15;
    const int kg   = lane >> 4;
    const int m0   = by * BM;
    const int n0   = bx * BN;
    const int kb   = blockIdx.z * Ksub;
    const int srow = tid >> 2;
    const int scol = (tid & 3) * 8;
    float* Cz = C + (size_t)blockIdx.z * czstride;

    floatx4 acc[MR][NR];
#pragma unroll
    for (int mi = 0; mi < MR; ++mi)
#pragma unroll
        for (int ni = 0; ni < NR; ++ni)
            acc[mi][ni] = (floatx4){0.f, 0.f, 0.f, 0.f};

    auto stage = [&](int buf, int k0) {
        __builtin_amdgcn_global_load_lds(
            (const GLB unsigned int*)&A[(size_t)(m0 + srow) * lda + k0 + scol],
            (LDSAS unsigned int*)&Alds[buf][tid * 8], 16, 0, 0);
#pragma unroll
        for (int r = 0; r < 2; ++r)
            __builtin_amdgcn_global_load_lds(
                (const GLB unsigned int*)&B[(size_t)(n0 + r * 64 + srow) * ldb + k0 + scol],
                (LDSAS unsigned int*)&Blds[buf][r * 2048 + tid * 8], 16, 0, 0);
    };

    const int nt = Ksub / BK;
    stage(0, kb);
    __syncthreads();
    int cur = 0;
    for (int t = 0; t < nt; ++t) {
        if (t + 1 < nt) stage(cur ^ 1, kb + (t + 1) * BK);
        short8 af[MR], bf[NR];
#pragma unroll
        for (int mi = 0; mi < MR; ++mi)
            af[mi] = *reinterpret_cast<const short8*>(
                &Alds[cur][(wm * 32 + mi * 16 + fr) * BK + kg * 8]);
#pragma unroll
        for (int ni = 0; ni < NR; ++ni)
            bf[ni] = *reinterpret_cast<const short8*>(
                &Blds[cur][(wn * 64 + ni * 16 + fr) * BK + kg * 8]);
#pragma unroll
        for (int mi = 0; mi < MR; ++mi)
#pragma unroll
            for (int ni = 0; ni < NR; ++ni)
                acc[mi][ni] = __builtin_amdgcn_mfma_f32_16x16x32_bf16(
                    af[mi], bf[ni], acc[mi][ni], 0, 0, 0);
        __syncthreads();
        cur ^= 1;
    }

#pragma unroll
    for (int mi = 0; mi < MR; ++mi)
#pragma unroll
        for (int ni = 0; ni < NR; ++ni)
#pragma unroll
            for (int r = 0; r < 4; ++r) {
                int row = m0 + wm * 32 + mi * 16 + kg * 4 + r;
                int col = n0 + wn * 64 + ni * 16 + fr;
                float v = acc[mi][ni][r];
                if constexpr (EPI == 1) {
                    v += bias[col];
                    v = (v > 20.f) ? v : log1pf(__expf(v));
                }
                Cz[(size_t)row * ldc + col] = v;
            }
}

// sum 8 split-K partials -> xdbl f32 + bf16
__global__ __launch_bounds__(256)
void combine_xdbl(const float* __restrict__ xp, float* __restrict__ xf,
                  unsigned short* __restrict__ xb)
{
    int i = (blockIdx.x * 256 + threadIdx.x) * 4;   // over SEQ*XPWP
    constexpr size_t SL = (size_t)SEQ * XPWP;
    float4 s{0.f, 0.f, 0.f, 0.f};
#pragma unroll
    for (int z = 0; z < 8; ++z) {
        float4 p = *reinterpret_cast<const float4*>(&xp[z * SL + i]);
        s.x += p.x; s.y += p.y; s.z += p.z; s.w += p.w;
    }
    *reinterpret_cast<float4*>(&xf[i]) = s;
    short4_t o; o[0]=(short)f2b(s.x); o[1]=(short)f2b(s.y);
                o[2]=(short)f2b(s.z); o[3]=(short)f2b(s.w);
    *reinterpret_cast<short4_t*>(&xb[i]) = o;
}

// sum 4 split-K partials -> final out
__global__ __launch_bounds__(256)
void combine_out(const float* __restrict__ op, float* __restrict__ out)
{
    int i = (blockIdx.x * 256 + threadIdx.x) * 4;   // over SEQ*DMODEL
    constexpr size_t SL = (size_t)SEQ * DMODEL;
    float4 s0 = *reinterpret_cast<const float4*>(&op[i]);
    float4 s1 = *reinterpret_cast<const float4*>(&op[SL + i]);
    float4 s2 = *reinterpret_cast<const float4*>(&op[2 * SL + i]);
    float4 s3 = *reinterpret_cast<const float4*>(&op[3 * SL + i]);
    float4 s{ s0.x+s1.x+s2.x+s3.x, s0.y+s1.y+s2.y+s3.y,
              s0.z+s1.z+s2.z+s3.z, s0.w+s1.w+s2.w+s3.w };
    *reinterpret_cast<float4*>(&out[i]) = s;
}

// causal depthwise conv (width 4) + bias + silu; xi = xz[:, 0:2048]; out bf16.
__global__ __launch_bounds__(256)
void conv_silu(const float* __restrict__ xz,
               const float* __restrict__ conv_w,
               const float* __restrict__ conv_b,
               unsigned short* __restrict__ xic)
{
    int idx = blockIdx.x * 256 + threadIdx.x;
    int l = idx / DINNER;
    int d = idx % DINNER;
    float acc = conv_b[d];
    float4 w = *reinterpret_cast<const float4*>(&conv_w[d * 4]);
    float wk[4] = {w.x, w.y, w.z, w.w};
#pragma unroll
    for (int k = 0; k < 4; ++k) {
        int ls = l - 3 + k;
        if (ls >= 0) acc = fmaf(xz[(size_t)ls * (2 * DINNER) + d], wk[k], acc);
    }
    xic[idx] = f2b(siluf(acc));
}

// ---------------- chunk-parallel selective scan, n-in-registers ----------------
__global__ __launch_bounds__(256)
void scan_pass1(const float* __restrict__ delta,
                const unsigned short* __restrict__ xic,
                const float* __restrict__ xdbl,     // f32 [SEQ][128], B at 64
                const float* __restrict__ A_log,
                float* __restrict__ Pbuf, float* __restrict__ Sbuf, int CH)
{
    const int tid = threadIdx.x;
    const int d   = blockIdx.x * 256 + tid;
    const int c   = blockIdx.y;
    const int tb  = c * CH;

    float An[16], h[16];
#pragma unroll
    for (int n = 0; n < 16; ++n) {
        An[n] = -__expf(A_log[(size_t)d * 16 + n]);
        h[n]  = 0.f;
    }
    float sdl = 0.f;

    __shared__ float Bls[16][16];
    const int sr = tid >> 4, sq = tid & 15;

    for (int s0 = 0; s0 < CH; s0 += 16) {
        Bls[sr][sq] = xdbl[(size_t)(tb + s0 + sr) * XPWP + DTRANK + sq];
        __syncthreads();
#pragma unroll
        for (int tt = 0; tt < 16; ++tt) {
            int t = tb + s0 + tt;
            float dl = delta[(size_t)t * DINNER + d];
            float xv = b2f(xic[(size_t)t * DINNER + d]);
            float t1 = dl * xv;
            sdl += dl;
            floatx4 B0 = *reinterpret_cast<const floatx4*>(&Bls[tt][0]);
            floatx4 B1 = *reinterpret_cast<const floatx4*>(&Bls[tt][4]);
            floatx4 B2 = *reinterpret_cast<const floatx4*>(&Bls[tt][8]);
            floatx4 B3 = *reinterpret_cast<const floatx4*>(&Bls[tt][12]);
#pragma unroll
            for (int n = 0; n < 16; ++n) {
                float bn = (n < 4) ? B0[n] : (n < 8) ? B1[n-4] : (n < 12) ? B2[n-8] : B3[n-12];
                float a  = __expf(dl * An[n]);
                h[n] = fmaf(a, h[n], t1 * bn);
            }
        }
        __syncthreads();
    }
#pragma unroll
    for (int n = 0; n < 16; ++n) {
        size_t o = ((size_t)c * 16 + n) * DINNER + d;
        Pbuf[o] = __expf(sdl * An[n]);
        Sbuf[o] = h[n];
    }
}

__global__ __launch_bounds__(256)
void scan_pass2(const float* __restrict__ Pbuf, float* __restrict__ Sbuf, int NCr)
{
    int idx = blockIdx.x * 256 + threadIdx.x;
    float h = 0.f;
    for (int c = 0; c < NCr; ++c) {
        size_t o = (size_t)c * (DINNER * DSTATE) + idx;
        float p = Pbuf[o], s = Sbuf[o];
        Sbuf[o] = h;
        h = fmaf(p, h, s);
    }
}

__global__ __launch_bounds__(256)
void scan_pass3(const float* __restrict__ delta,
                const unsigned short* __restrict__ xic,
                const float* __restrict__ xdbl,
                const float* __restrict__ A_log,
                const float* __restrict__ D_skip,
                const float* __restrict__ xz,
                const float* __restrict__ Hin,
                unsigned short* __restrict__ yfin, int CH)
{
    const int tid = threadIdx.x;
    const int d   = blockIdx.x * 256 + tid;
    const int c   = blockIdx.y;
    const int tb  = c * CH;

    float An[16], h[16];
#pragma unroll
    for (int n = 0; n < 16; ++n) {
        An[n] = -__expf(A_log[(size_t)d * 16 + n]);
        h[n]  = Hin[((size_t)c * 16 + n) * DINNER + d];
    }
    const float Dsk = D_skip[d];

    __shared__ float Bls[16][32];
    const int sr = tid >> 4, sq = (tid & 15) * 2;

    for (int s0 = 0; s0 < CH; s0 += 16) {
        float2 bc = *reinterpret_cast<const float2*>(
            &xdbl[(size_t)(tb + s0 + sr) * XPWP + DTRANK + sq]);
        Bls[sr][sq] = bc.x; Bls[sr][sq + 1] = bc.y;
        __syncthreads();
#pragma unroll
        for (int tt = 0; tt < 16; ++tt) {
            int t = tb + s0 + tt;
            float dl = delta[(size_t)t * DINNER + d];
            float xv = b2f(xic[(size_t)t * DINNER + d]);
            float zv = xz[(size_t)t * (2 * DINNER) + DINNER + d];
            float t1 = dl * xv;
            floatx4 B0 = *reinterpret_cast<const floatx4*>(&Bls[tt][0]);
            floatx4 B1 = *reinterpret_cast<const floatx4*>(&Bls[tt][4]);
            floatx4 B2 = *reinterpret_cast<const floatx4*>(&Bls[tt][8]);
            floatx4 B3 = *reinterpret_cast<const floatx4*>(&Bls[tt][12]);
            floatx4 C0 = *reinterpret_cast<const floatx4*>(&Bls[tt][16]);
            floatx4 C1 = *reinterpret_cast<const floatx4*>(&Bls[tt][20]);
            floatx4 C2 = *reinterpret_cast<const floatx4*>(&Bls[tt][24]);
            floatx4 C3 = *reinterpret_cast<const floatx4*>(&Bls[tt][28]);
            float y = 0.f;
#pragma unroll
            for (int n = 0; n < 16; ++n) {
                float bn = (n < 4) ? B0[n] : (n < 8) ? B1[n-4] : (n < 12) ? B2[n-8] : B3[n-12];
                float cn = (n < 4) ? C0[n] : (n < 8) ? C1[n-4] : (n < 12) ? C2[n-8] : C3[n-12];
                float a  = __expf(dl * An[n]);
                h[n] = fmaf(a, h[n], t1 * bn);
                y = fmaf(h[n], cn, y);
            }
            float yv = fmaf(xv, Dsk, y) * siluf(zv);
            yfin[(size_t)t * DINNER + d] = f2b(yv);
        }
        __syncthreads();
    }
}

}  // namespace

extern "C" void kernel_launch(void* const* d_in, const int* in_sizes, int n_in,
                              void* d_out, int out_size, void* d_ws, size_t ws_size,
                              hipStream_t stream)
{
    (void)in_sizes; (void)n_in; (void)out_size;

    const float* x       = (const float*)d_in[0];
    const float* W_in    = (const float*)d_in[1];
    const float* conv_w  = (const float*)d_in[2];
    const float* conv_b  = (const float*)d_in[3];
    const float* W_xproj = (const float*)d_in[4];
    const float* W_dt    = (const float*)d_in[5];
    const float* b_dt    = (const float*)d_in[6];
    const float* A_log   = (const float*)d_in[7];
    const float* D_skip  = (const float*)d_in[8];
    const float* W_out   = (const float*)d_in[9];
    float* out = (float*)d_out;

    // ---- pick NC by workspace budget ----
    const size_t BF16_SHORTS = CO5 + (size_t)SEQ * DINNER + (size_t)SEQ * XPWP
                             + (size_t)SEQ * DINNER;
    const size_t F32_FIXED   = (size_t)SEQ * 2 * DINNER       // xz (also op6 partials)
                             + (size_t)SEQ * DINNER           // delta
                             + (size_t)SEQ * XPWP             // xdbl_f
                             + 8 * (size_t)SEQ * XPWP;        // xpart (op3, 8 slabs)
    auto need = [&](int nc) {
        return (F32_FIXED + 2 * (size_t)nc * DINNER * DSTATE) * 4 + BF16_SHORTS * 2;
    };
    int NC = 64;
    if (need(64) > ws_size) NC = 32;
    if (need(32) > ws_size) NC = 16;
    const int CH = SEQ / NC;

    // ---- workspace carve ----
    float* ws     = (float*)d_ws;
    float* xz     = ws;                                   // SEQ*4096 (reused as op6 partials)
    float* delta  = xz    + (size_t)SEQ * 2 * DINNER;
    float* xdbl_f = delta + (size_t)SEQ * DINNER;
    float* xpart  = xdbl_f + (size_t)SEQ * XPWP;          // 8*SEQ*128
    float* Pbuf   = xpart + 8 * (size_t)SEQ * XPWP;
    float* Sbuf   = Pbuf  + (size_t)NC * DINNER * DSTATE;
    unsigned short* us     = (unsigned short*)(Sbuf + (size_t)NC * DINNER * DSTATE);
    unsigned short* x_b    = us;
    unsigned short* Win_b  = x_b + CO1;
    unsigned short* Wxp_b  = x_b + CO2;
    unsigned short* Wdt_b  = x_b + CO3;
    unsigned short* Wout_b = x_b + CO4;
    unsigned short* xic_b  = x_b + CO5;
    unsigned short* xdbl_b = xic_b + (size_t)SEQ * DINNER;
    unsigned short* yfin_b = xdbl_b + (size_t)SEQ * XPWP;
    float* opart = xz;   // op6 split-K partials (xz dead after scan_pass3)

    // 0) all bf16 casts
    cast_all<<<(int)((CO5 / 8 + 255) / 256), 256, 0, stream>>>(
        x, W_in, W_xproj, W_dt, W_out, x_b);

    // 1) xz = x @ W_in^T   (1024 x 4096, K=1024): 32x16 = 512 blocks
    gemm_mfma<0><<<dim3(512, 1, 1), 256, 0, stream>>>(
        x_b, DMODEL, Win_b, DMODEL, xz, 2 * DINNER, 0, nullptr, DMODEL, 32);

    // 2) conv + silu -> xic (bf16)
    conv_silu<<<(SEQ * DINNER) / 256, 256, 0, stream>>>(xz, conv_w, conv_b, xic_b);

    // 3) x_dbl = xic @ W_xproj^T, split-K=8  (1024 x 128, K=2048): 16 x 8z
    gemm_mfma<0><<<dim3(16, 1, 8), 256, 0, stream>>>(
        xic_b, DINNER, Wxp_b, DINNER, xpart, XPWP, (size_t)SEQ * XPWP,
        nullptr, DINNER / 8, 1);
    combine_xdbl<<<(SEQ * XPWP) / 1024, 256, 0, stream>>>(xpart, xdbl_f, xdbl_b);

    // 4) delta = softplus(dt @ W_dt^T + b_dt)  (1024 x 2048, K=64): 16x16 = 256
    gemm_mfma<1><<<dim3(256, 1, 1), 256, 0, stream>>>(
        xdbl_b, XPWP, Wdt_b, DTRANK, delta, DINNER, 0, b_dt, DTRANK, 16);

    // 5) chunk-parallel selective scan + gate fusion
    scan_pass1<<<dim3(DINNER / 256, NC), 256, 0, stream>>>(
        delta, xic_b, xdbl_f, A_log, Pbuf, Sbuf, CH);
    scan_pass2<<<(DINNER * DSTATE) / 256, 256, 0, stream>>>(Pbuf, Sbuf, NC);
    scan_pass3<<<dim3(DINNER / 256, NC), 256, 0, stream>>>(
        delta, xic_b, xdbl_f, A_log, D_skip, xz, Sbuf, yfin_b, CH);

    // 6) out = y @ W_out^T, split-K=4  (1024 x 1024, K=2048): 8x16 x 4z = 512
    gemm_mfma<0><<<dim3(128, 1, 4), 256, 0, stream>>>(
        yfin_b, DINNER, Wout_b, DINNER, opart, DMODEL, (size_t)SEQ * DMODEL,
        nullptr, DINNER / 4, 8);
    combine_out<<<(SEQ * DMODEL) / 1024, 256, 0, stream>>>(opart, out);
}